// Round 3
// baseline (408.505 us; speedup 1.0000x reference)
//
#include <hip/hip_runtime.h>
#include <float.h>

// QKV attention, qkv [2,3072,2048] f32, mask [2,1,2048] i32, out [2,1024,2048] f32.
// Prep: f32->bf16; Q -> [bh][t][c] (pre-scaled 1/8*log2e); K,V -> FRAG-MAJOR:
// per (head, s-tile, frag) a 64-lane x 16B contiguous block == one coalesced
// 1KB wave load that lands directly in MFMA A/B layout.
// Main: barrier-free flash loop. R3: push occupancy to the grid max —
// 32-row q-tiles, grid 2048 (= 8 blocks/CU nominal, 32 waves/CU), 4 waves
// each own an s-quarter. Mask bias array (8KB f32) replaced by 2KB byte
// flags (2 extra cndmask/elem) so LDS fits 8 blocks/CU (18.9KB);
// __launch_bounds__(256,8) pins VGPR<=64 (R2 already compiled at 64).
// head=blk&31 keeps each head's K/V pinned to one XCD's L2 (2MB/XCD).
// Epilogue: 4-way l/O combine through LDS (reused as 2 f32 O-buffers).

typedef __attribute__((ext_vector_type(8))) short bf16x8;
typedef __attribute__((ext_vector_type(4))) float f32x4;

#define TSEQ 2048
#define QT_OFF 0L
#define KF_OFF 4194304L
#define VF_OFF 8388608L

#if __has_builtin(__builtin_amdgcn_exp2f)
#define EXPFN(x) __builtin_amdgcn_exp2f(x)
#define SM_SCALE (0.125f * 1.44269504088896f)
#else
#define EXPFN(x) __expf(x)
#define SM_SCALE 0.125f
#endif

__device__ inline short f2bf(float x) {
    union { float f; unsigned u; } un; un.f = x;
    unsigned r = un.u + 0x7fffu + ((un.u >> 16) & 1u);  // RNE
    return (short)(r >> 16);
}

// pack two nonneg floats to bf16 pair, round-half-up: 1 add each + 1 perm
__device__ inline unsigned pkbf(float a, float b) {
    unsigned au = __float_as_uint(a) + 0x8000u;
    unsigned bu = __float_as_uint(b) + 0x8000u;
    return __builtin_amdgcn_perm(bu, au, 0x07060302u);  // [a_hi16 | b_hi16<<16]
}

// ---------------- pre-pass: convert + reorder ----------------
__global__ __launch_bounds__(256) void prep_kernel(
    const float* __restrict__ qkv, short* __restrict__ ws)
{
    const int tid = threadIdx.x;
    const int job = blockIdx.x;
    if (job < 2048) {
        __shared__ float Ls[64 * 65];   // [c][t]
        const int which = job & 1;      // 0=Q 1=K
        const int rest  = job >> 1;
        const int bh = rest & 31, tt = rest >> 5;
        const int b = bh >> 4, h = bh & 15;
        const float* src = qkv + (long)b * 6291456 + ((long)(which * 1024 + h * 64)) * TSEQ + tt * 64;
        #pragma unroll
        for (int ch = 0; ch < 4; ++ch) {
            int idx = tid + ch * 256;
            int c = idx >> 4, tch = idx & 15;
            float4 v = *(const float4*)(src + (long)c * TSEQ + tch * 4);
            float* L = &Ls[c * 65 + tch * 4];
            L[0] = v.x; L[1] = v.y; L[2] = v.z; L[3] = v.w;
        }
        __syncthreads();
        if (which == 0) {
            // Q -> [t][c], scaled
            short* dst = ws + QT_OFF + ((long)bh * TSEQ + tt * 64) * 64;
            #pragma unroll
            for (int ch = 0; ch < 2; ++ch) {
                int idx = tid + ch * 256;
                int t = idx >> 3, cch = idx & 7;
                bf16x8 o;
                #pragma unroll
                for (int j = 0; j < 8; ++j)
                    o[j] = f2bf(Ls[(cch * 8 + j) * 65 + t] * SM_SCALE);
                *(bf16x8*)(dst + (long)t * 64 + cch * 8) = o;
            }
        } else {
            // K -> frag-major: unit (f=ns*2+hf, lane) = K[s=tt*64+ns*16+l15][c=hf*32+q*8+j]
            short* dst = ws + KF_OFF + (long)(bh * 32 + tt) * 4096;
            #pragma unroll
            for (int ch = 0; ch < 2; ++ch) {
                int u = tid + ch * 256;             // 0..511
                int f = u >> 6, lane = u & 63;
                int q = lane >> 4, l15 = lane & 15;
                int hf = f & 1, ns = f >> 1;
                bf16x8 o;
                #pragma unroll
                for (int j = 0; j < 8; ++j)
                    o[j] = f2bf(Ls[(hf * 32 + q * 8 + j) * 65 + ns * 16 + l15]);
                *(bf16x8*)(dst + f * 512 + lane * 8) = o;
            }
        }
    } else {
        // V -> frag-major: unit (f=nc*2+hf, lane) = V[c=nc*16+l15][s=it*64+hf*32+q*8+j]
        const int v = job - 2048;               // 0..1023
        const int head = v >> 5, it = v & 31;
        const int b = head >> 4, h = head & 15;
        short* dst = ws + VF_OFF + (long)(head * 32 + it) * 4096;
        #pragma unroll
        for (int ch = 0; ch < 2; ++ch) {
            int u = tid + ch * 256;             // 0..511
            int f = u >> 6, lane = u & 63;
            int q = lane >> 4, l15 = lane & 15;
            int hf = f & 1, nc = f >> 1;
            const float* src = qkv + (long)b * 6291456
                + ((long)(2048 + h * 64 + nc * 16 + l15)) * TSEQ
                + it * 64 + hf * 32 + q * 8;
            float4 a  = *(const float4*)src;
            float4 c4 = *(const float4*)(src + 4);
            bf16x8 o;
            o[0] = f2bf(a.x);  o[1] = f2bf(a.y);  o[2] = f2bf(a.z);  o[3] = f2bf(a.w);
            o[4] = f2bf(c4.x); o[5] = f2bf(c4.y); o[6] = f2bf(c4.z); o[7] = f2bf(c4.w);
            *(bf16x8*)(dst + f * 512 + lane * 8) = o;
        }
    }
}

// ---------------- main attention (32 q-rows, 4 waves x s-quarters) ----------------
__global__ __launch_bounds__(256, 8) void attn_kernel(
    const short* __restrict__ wsp, const int* __restrict__ mask,
    float* __restrict__ out)
{
    __shared__ __align__(16) char smem[18944];
    short* Ps = (short*)smem;                            // 4 waves x 4KB P round-trip
    unsigned char* mfl = (unsigned char*)(smem + 16384); // 2KB: 1 valid / 0 masked
    float* Os0 = (float*)smem;                           // epilogue [64][36] f32
    float* Os1 = (float*)(smem + 9216);                  // epilogue [64][36] f32
    float* Lc  = (float*)(smem + 18432);                 // 128 f32 l-combine

    const int tid  = threadIdx.x;
    const int lane = tid & 63, wid = tid >> 6;      // wid 0..3 = s-quarter
    const int l15  = lane & 15, quad = lane >> 4;

    const int blk  = blockIdx.x;             // 0..2047
    const int head = blk & 31;               // all blocks of a head -> XCD head%8
    const int qt   = blk >> 5;               // 0..63
    const int b    = head >> 4, h = head & 15;
    const int t0   = qt * 32;

    const short* QT = wsp + QT_OFF + (long)head * 131072;   // [t][c]
    const short* KF = wsp + KF_OFF + (long)head * 131072;   // frag-major
    const short* VF = wsp + VF_OFF + (long)head * 131072;   // frag-major
    const long obase = ((long)b * 1024 + h * 64) * TSEQ;

    for (int i = tid; i < TSEQ; i += 256)
        mfl[i] = (mask[b * TSEQ + i] != 0) ? 1 : 0;
    __syncthreads();

    // Q frags (same 32 rows for all 4 waves; L1-served redundancy)
    bf16x8 qb[2][2];
    #pragma unroll
    for (int nt = 0; nt < 2; ++nt)
        #pragma unroll
        for (int hf = 0; hf < 2; ++hf)
            qb[nt][hf] = *(const bf16x8*)(QT +
                (long)(t0 + nt * 16 + l15) * 64 + quad * 8 + hf * 32);
    bool qm[2];   // true = q row masked -> uniform row (pv=1)
    #pragma unroll
    for (int nt = 0; nt < 2; ++nt)
        qm[nt] = (mask[b * TSEQ + t0 + nt * 16 + l15] == 0);

    float l_s[2] = {0.0f, 0.0f};
    f32x4 Oacc[2][4];
    #pragma unroll
    for (int mt = 0; mt < 2; ++mt)
        #pragma unroll
        for (int nc = 0; nc < 4; ++nc)
            #pragma unroll
            for (int r = 0; r < 4; ++r) Oacc[mt][nc][r] = 0.0f;

    short* Pw = Ps + wid * 2048;
    const short* KL = KF + lane * 8;
    const short* VL = VF + lane * 8;
    const f32x4 zc = {0.0f, 0.0f, 0.0f, 0.0f};

    // s-quarters interleaved: wave wid does tiles wid, wid+4, ... (8 tiles)
    for (int i = 0; i < 8; ++i) {
        const int it = wid + i * 4;

        // K frags (8 coalesced 1KB wave loads, L2-resident stream)
        const short* kp = KL + (long)it * 4096;
        bf16x8 kc[8];
        #pragma unroll
        for (int f = 0; f < 8; ++f)
            kc[f] = *(const bf16x8*)(kp + f * 512);

        // s-mask flags: 4B broadcast LDS reads (one word per ns)
        unsigned fw[4];
        #pragma unroll
        for (int ns = 0; ns < 4; ++ns)
            fw[ns] = *(const unsigned*)(mfl + it * 64 + ns * 16 + quad * 4);

        // S^T = K Q^T (zero C-init; mask applied post-exp)
        f32x4 Sacc[4][2];
        __builtin_amdgcn_s_setprio(1);
        #pragma unroll
        for (int ns = 0; ns < 4; ++ns)
            #pragma unroll
            for (int nt = 0; nt < 2; ++nt) {
                Sacc[ns][nt] = __builtin_amdgcn_mfma_f32_16x16x32_bf16(
                    kc[ns * 2 + 0], qb[nt][0], zc, 0, 0, 0);
                Sacc[ns][nt] = __builtin_amdgcn_mfma_f32_16x16x32_bf16(
                    kc[ns * 2 + 1], qb[nt][1], Sacc[ns][nt], 0, 0, 0);
            }
        __builtin_amdgcn_s_setprio(0);

        // fixed-max softmax; P write with XOR-swizzled layout (<=2-way banks)
        #pragma unroll
        for (int nt = 0; nt < 2; ++nt) {
            const int row = nt * 16 + l15;
            const int sw  = (row & 7) ^ ((row & 8) >> 1);
            float ls = 0.0f;
            #pragma unroll
            for (int ns = 0; ns < 4; ++ns) {
                float pv[4];
                #pragma unroll
                for (int r = 0; r < 4; ++r) {
                    float e = EXPFN(Sacc[ns][nt][r]);
                    float em = ((fw[ns] >> (r * 8)) & 0xffu) ? e : 0.0f;
                    pv[r] = qm[nt] ? 1.0f : em;
                    ls += pv[r];
                }
                const int cbp = (ns * 2 + (quad >> 1)) ^ sw;
                uint2 pk;
                pk.x = pkbf(pv[0], pv[1]);
                pk.y = pkbf(pv[2], pv[3]);
                *(uint2*)&Pw[row * 64 + cbp * 8 + (quad & 1) * 4] = pk;
            }
            ls += __shfl_xor(ls, 16);
            ls += __shfl_xor(ls, 32);
            l_s[nt] += ls;
        }

        // V frags (issued between P write and P read; TLP hides latency)
        const short* vp = VL + (long)it * 4096;
        bf16x8 vf[8];
        #pragma unroll
        for (int f = 0; f < 8; ++f)
            vf[f] = *(const bf16x8*)(vp + f * 512);

        // P read (same swizzle) + O += P V^T
        bf16x8 pa[2][2];
        #pragma unroll
        for (int mt = 0; mt < 2; ++mt) {
            const int row = mt * 16 + l15;
            const int sw  = (row & 7) ^ ((row & 8) >> 1);
            #pragma unroll
            for (int hf = 0; hf < 2; ++hf)
                pa[mt][hf] = *(const bf16x8*)&Pw[row * 64 + ((quad + 4 * hf) ^ sw) * 8];
        }
        __builtin_amdgcn_s_setprio(1);
        #pragma unroll
        for (int hf = 0; hf < 2; ++hf)
            #pragma unroll
            for (int nc = 0; nc < 4; ++nc)
                #pragma unroll
                for (int mt = 0; mt < 2; ++mt)
                    Oacc[mt][nc] = __builtin_amdgcn_mfma_f32_16x16x32_bf16(
                        pa[mt][hf], vf[nc * 2 + hf], Oacc[mt][nc], 0, 0, 0);
        __builtin_amdgcn_s_setprio(0);
    }

    // ---- epilogue: 4-way combine of l and O, scale, store ----
    __syncthreads();                         // loop done: Ps region reusable soon
    if (quad == 0) {
        Lc[wid * 32 + l15]      = l_s[0];
        Lc[wid * 32 + 16 + l15] = l_s[1];
    }
    __syncthreads();
    float inv[2];
    #pragma unroll
    for (int nt = 0; nt < 2; ++nt) {
        const int off = nt * 16 + l15;
        inv[nt] = 1.0f / (Lc[off] + Lc[32 + off] + Lc[64 + off] + Lc[96 + off]);
    }
    float iw[2][4];
    #pragma unroll
    for (int mt = 0; mt < 2; ++mt)
        #pragma unroll
        for (int r = 0; r < 4; ++r)
            iw[mt][r] = __shfl(inv[mt], 4 * quad + r);

    float* Om = (wid & 1) ? Os1 : Os0;
    if (wid < 2) {
        #pragma unroll
        for (int mt = 0; mt < 2; ++mt)
            #pragma unroll
            for (int nc = 0; nc < 4; ++nc) {
                float4 o;
                o.x = Oacc[mt][nc][0] * iw[mt][0];
                o.y = Oacc[mt][nc][1] * iw[mt][1];
                o.z = Oacc[mt][nc][2] * iw[mt][2];
                o.w = Oacc[mt][nc][3] * iw[mt][3];
                *(float4*)&Om[(nc * 16 + l15) * 36 + mt * 16 + quad * 4] = o;
            }
    }
    __syncthreads();
    if (wid >= 2) {
        #pragma unroll
        for (int mt = 0; mt < 2; ++mt)
            #pragma unroll
            for (int nc = 0; nc < 4; ++nc) {
                float* p = &Om[(nc * 16 + l15) * 36 + mt * 16 + quad * 4];
                p[0] += Oacc[mt][nc][0] * iw[mt][0];
                p[1] += Oacc[mt][nc][1] * iw[mt][1];
                p[2] += Oacc[mt][nc][2] * iw[mt][2];
                p[3] += Oacc[mt][nc][3] * iw[mt][3];
            }
    }
    __syncthreads();
    #pragma unroll
    for (int ch = 0; ch < 2; ++ch) {
        int idx = tid + ch * 256;           // 0..511
        int c = idx >> 3, tch = idx & 7;
        f32x4 o0 = *(const f32x4*)&Os0[c * 36 + tch * 4];
        f32x4 o1 = *(const f32x4*)&Os1[c * 36 + tch * 4];
        f32x4 o = o0 + o1;
        *(f32x4*)(out + obase + (long)c * TSEQ + t0 + tch * 4) = o;
    }
}

extern "C" void kernel_launch(void* const* d_in, const int* in_sizes, int n_in,
                              void* d_out, int out_size, void* d_ws, size_t ws_size,
                              hipStream_t stream) {
    const float* qkv  = (const float*)d_in[0];
    const int*   mask = (const int*)d_in[1];
    float*       out  = (float*)d_out;
    short*       ws   = (short*)d_ws;       // needs 24 MiB
    prep_kernel<<<dim3(3072), dim3(256), 0, stream>>>(qkv, ws);
    attn_kernel<<<dim3(2048), dim3(256), 0, stream>>>(ws, mask, out);
}

// Round 4
// 141.138 us; speedup vs baseline: 2.8944x; 2.8944x over previous
//
#include <hip/hip_runtime.h>
#include <float.h>

// QKV attention, qkv [2,3072,2048] f32, mask [2,1,2048] i32, out [2,1024,2048] f32.
// Prep: f32->bf16; Q -> [bh][t][c] (pre-scaled 1/8*log2e); K,V -> FRAG-MAJOR:
// per (head, s-tile, frag) a 64-lane x 16B contiguous block == one coalesced
// 1KB wave load that lands directly in MFMA A/B layout.
// Main: barrier-free flash loop. R4 = R3 structure (32-row q-tiles, grid 2048,
// 4 waves x s-quarters, 2KB byte-flag mask, 18.9KB LDS -> 8 blocks/CU ceiling)
// with the launch bound REVERTED to (256,4): R3's (256,8) forced the compiler
// to a 32-VGPR budget and spilled the whole working set (FETCH 12MB->662MB,
// 6x regression). The structure needs ~64 VGPR (proven by R2's identical
// footprint compiling to exactly 64 under (256,4)); 64 VGPR == the HW
// 8-waves/SIMD boundary, so the scheduler can still pack 8 blocks/CU.

typedef __attribute__((ext_vector_type(8))) short bf16x8;
typedef __attribute__((ext_vector_type(4))) float f32x4;

#define TSEQ 2048
#define QT_OFF 0L
#define KF_OFF 4194304L
#define VF_OFF 8388608L

#if __has_builtin(__builtin_amdgcn_exp2f)
#define EXPFN(x) __builtin_amdgcn_exp2f(x)
#define SM_SCALE (0.125f * 1.44269504088896f)
#else
#define EXPFN(x) __expf(x)
#define SM_SCALE 0.125f
#endif

__device__ inline short f2bf(float x) {
    union { float f; unsigned u; } un; un.f = x;
    unsigned r = un.u + 0x7fffu + ((un.u >> 16) & 1u);  // RNE
    return (short)(r >> 16);
}

// pack two nonneg floats to bf16 pair, round-half-up: 1 add each + 1 perm
__device__ inline unsigned pkbf(float a, float b) {
    unsigned au = __float_as_uint(a) + 0x8000u;
    unsigned bu = __float_as_uint(b) + 0x8000u;
    return __builtin_amdgcn_perm(bu, au, 0x07060302u);  // [a_hi16 | b_hi16<<16]
}

// ---------------- pre-pass: convert + reorder ----------------
__global__ __launch_bounds__(256) void prep_kernel(
    const float* __restrict__ qkv, short* __restrict__ ws)
{
    const int tid = threadIdx.x;
    const int job = blockIdx.x;
    if (job < 2048) {
        __shared__ float Ls[64 * 65];   // [c][t]
        const int which = job & 1;      // 0=Q 1=K
        const int rest  = job >> 1;
        const int bh = rest & 31, tt = rest >> 5;
        const int b = bh >> 4, h = bh & 15;
        const float* src = qkv + (long)b * 6291456 + ((long)(which * 1024 + h * 64)) * TSEQ + tt * 64;
        #pragma unroll
        for (int ch = 0; ch < 4; ++ch) {
            int idx = tid + ch * 256;
            int c = idx >> 4, tch = idx & 15;
            float4 v = *(const float4*)(src + (long)c * TSEQ + tch * 4);
            float* L = &Ls[c * 65 + tch * 4];
            L[0] = v.x; L[1] = v.y; L[2] = v.z; L[3] = v.w;
        }
        __syncthreads();
        if (which == 0) {
            // Q -> [t][c], scaled
            short* dst = ws + QT_OFF + ((long)bh * TSEQ + tt * 64) * 64;
            #pragma unroll
            for (int ch = 0; ch < 2; ++ch) {
                int idx = tid + ch * 256;
                int t = idx >> 3, cch = idx & 7;
                bf16x8 o;
                #pragma unroll
                for (int j = 0; j < 8; ++j)
                    o[j] = f2bf(Ls[(cch * 8 + j) * 65 + t] * SM_SCALE);
                *(bf16x8*)(dst + (long)t * 64 + cch * 8) = o;
            }
        } else {
            // K -> frag-major: unit (f=ns*2+hf, lane) = K[s=tt*64+ns*16+l15][c=hf*32+q*8+j]
            short* dst = ws + KF_OFF + (long)(bh * 32 + tt) * 4096;
            #pragma unroll
            for (int ch = 0; ch < 2; ++ch) {
                int u = tid + ch * 256;             // 0..511
                int f = u >> 6, lane = u & 63;
                int q = lane >> 4, l15 = lane & 15;
                int hf = f & 1, ns = f >> 1;
                bf16x8 o;
                #pragma unroll
                for (int j = 0; j < 8; ++j)
                    o[j] = f2bf(Ls[(hf * 32 + q * 8 + j) * 65 + ns * 16 + l15]);
                *(bf16x8*)(dst + f * 512 + lane * 8) = o;
            }
        }
    } else {
        // V -> frag-major: unit (f=nc*2+hf, lane) = V[c=nc*16+l15][s=it*64+hf*32+q*8+j]
        const int v = job - 2048;               // 0..1023
        const int head = v >> 5, it = v & 31;
        const int b = head >> 4, h = head & 15;
        short* dst = ws + VF_OFF + (long)(head * 32 + it) * 4096;
        #pragma unroll
        for (int ch = 0; ch < 2; ++ch) {
            int u = tid + ch * 256;             // 0..511
            int f = u >> 6, lane = u & 63;
            int q = lane >> 4, l15 = lane & 15;
            int hf = f & 1, nc = f >> 1;
            const float* src = qkv + (long)b * 6291456
                + ((long)(2048 + h * 64 + nc * 16 + l15)) * TSEQ
                + it * 64 + hf * 32 + q * 8;
            float4 a  = *(const float4*)src;
            float4 c4 = *(const float4*)(src + 4);
            bf16x8 o;
            o[0] = f2bf(a.x);  o[1] = f2bf(a.y);  o[2] = f2bf(a.z);  o[3] = f2bf(a.w);
            o[4] = f2bf(c4.x); o[5] = f2bf(c4.y); o[6] = f2bf(c4.z); o[7] = f2bf(c4.w);
            *(bf16x8*)(dst + f * 512 + lane * 8) = o;
        }
    }
}

// ---------------- main attention (32 q-rows, 4 waves x s-quarters) ----------------
__global__ __launch_bounds__(256, 4) void attn_kernel(
    const short* __restrict__ wsp, const int* __restrict__ mask,
    float* __restrict__ out)
{
    __shared__ __align__(16) char smem[18944];
    short* Ps = (short*)smem;                            // 4 waves x 4KB P round-trip
    unsigned char* mfl = (unsigned char*)(smem + 16384); // 2KB: 1 valid / 0 masked
    float* Os0 = (float*)smem;                           // epilogue [64][36] f32
    float* Os1 = (float*)(smem + 9216);                  // epilogue [64][36] f32
    float* Lc  = (float*)(smem + 18432);                 // 128 f32 l-combine

    const int tid  = threadIdx.x;
    const int lane = tid & 63, wid = tid >> 6;      // wid 0..3 = s-quarter
    const int l15  = lane & 15, quad = lane >> 4;

    const int blk  = blockIdx.x;             // 0..2047
    const int head = blk & 31;               // all blocks of a head -> XCD head%8
    const int qt   = blk >> 5;               // 0..63
    const int b    = head >> 4, h = head & 15;
    const int t0   = qt * 32;

    const short* QT = wsp + QT_OFF + (long)head * 131072;   // [t][c]
    const short* KF = wsp + KF_OFF + (long)head * 131072;   // frag-major
    const short* VF = wsp + VF_OFF + (long)head * 131072;   // frag-major
    const long obase = ((long)b * 1024 + h * 64) * TSEQ;

    for (int i = tid; i < TSEQ; i += 256)
        mfl[i] = (mask[b * TSEQ + i] != 0) ? 1 : 0;
    __syncthreads();

    // Q frags (same 32 rows for all 4 waves; L1-served redundancy)
    bf16x8 qb[2][2];
    #pragma unroll
    for (int nt = 0; nt < 2; ++nt)
        #pragma unroll
        for (int hf = 0; hf < 2; ++hf)
            qb[nt][hf] = *(const bf16x8*)(QT +
                (long)(t0 + nt * 16 + l15) * 64 + quad * 8 + hf * 32);
    bool qm[2];   // true = q row masked -> uniform row (pv=1)
    #pragma unroll
    for (int nt = 0; nt < 2; ++nt)
        qm[nt] = (mask[b * TSEQ + t0 + nt * 16 + l15] == 0);

    float l_s[2] = {0.0f, 0.0f};
    f32x4 Oacc[2][4];
    #pragma unroll
    for (int mt = 0; mt < 2; ++mt)
        #pragma unroll
        for (int nc = 0; nc < 4; ++nc)
            #pragma unroll
            for (int r = 0; r < 4; ++r) Oacc[mt][nc][r] = 0.0f;

    short* Pw = Ps + wid * 2048;
    const short* KL = KF + lane * 8;
    const short* VL = VF + lane * 8;
    const f32x4 zc = {0.0f, 0.0f, 0.0f, 0.0f};

    // s-quarters interleaved: wave wid does tiles wid, wid+4, ... (8 tiles)
    for (int i = 0; i < 8; ++i) {
        const int it = wid + i * 4;

        // K frags (8 coalesced 1KB wave loads, L2-resident stream)
        const short* kp = KL + (long)it * 4096;
        bf16x8 kc[8];
        #pragma unroll
        for (int f = 0; f < 8; ++f)
            kc[f] = *(const bf16x8*)(kp + f * 512);

        // s-mask flags: 4B broadcast LDS reads (one word per ns)
        unsigned fw[4];
        #pragma unroll
        for (int ns = 0; ns < 4; ++ns)
            fw[ns] = *(const unsigned*)(mfl + it * 64 + ns * 16 + quad * 4);

        // S^T = K Q^T (zero C-init; mask applied post-exp)
        f32x4 Sacc[4][2];
        __builtin_amdgcn_s_setprio(1);
        #pragma unroll
        for (int ns = 0; ns < 4; ++ns)
            #pragma unroll
            for (int nt = 0; nt < 2; ++nt) {
                Sacc[ns][nt] = __builtin_amdgcn_mfma_f32_16x16x32_bf16(
                    kc[ns * 2 + 0], qb[nt][0], zc, 0, 0, 0);
                Sacc[ns][nt] = __builtin_amdgcn_mfma_f32_16x16x32_bf16(
                    kc[ns * 2 + 1], qb[nt][1], Sacc[ns][nt], 0, 0, 0);
            }
        __builtin_amdgcn_s_setprio(0);

        // fixed-max softmax; P write with XOR-swizzled layout (<=2-way banks)
        #pragma unroll
        for (int nt = 0; nt < 2; ++nt) {
            const int row = nt * 16 + l15;
            const int sw  = (row & 7) ^ ((row & 8) >> 1);
            float ls = 0.0f;
            #pragma unroll
            for (int ns = 0; ns < 4; ++ns) {
                float pv[4];
                #pragma unroll
                for (int r = 0; r < 4; ++r) {
                    float e = EXPFN(Sacc[ns][nt][r]);
                    float em = ((fw[ns] >> (r * 8)) & 0xffu) ? e : 0.0f;
                    pv[r] = qm[nt] ? 1.0f : em;
                    ls += pv[r];
                }
                const int cbp = (ns * 2 + (quad >> 1)) ^ sw;
                uint2 pk;
                pk.x = pkbf(pv[0], pv[1]);
                pk.y = pkbf(pv[2], pv[3]);
                *(uint2*)&Pw[row * 64 + cbp * 8 + (quad & 1) * 4] = pk;
            }
            ls += __shfl_xor(ls, 16);
            ls += __shfl_xor(ls, 32);
            l_s[nt] += ls;
        }

        // V frags (issued between P write and P read; TLP hides latency)
        const short* vp = VL + (long)it * 4096;
        bf16x8 vf[8];
        #pragma unroll
        for (int f = 0; f < 8; ++f)
            vf[f] = *(const bf16x8*)(vp + f * 512);

        // P read (same swizzle) + O += P V^T
        bf16x8 pa[2][2];
        #pragma unroll
        for (int mt = 0; mt < 2; ++mt) {
            const int row = mt * 16 + l15;
            const int sw  = (row & 7) ^ ((row & 8) >> 1);
            #pragma unroll
            for (int hf = 0; hf < 2; ++hf)
                pa[mt][hf] = *(const bf16x8*)&Pw[row * 64 + ((quad + 4 * hf) ^ sw) * 8];
        }
        __builtin_amdgcn_s_setprio(1);
        #pragma unroll
        for (int hf = 0; hf < 2; ++hf)
            #pragma unroll
            for (int nc = 0; nc < 4; ++nc)
                #pragma unroll
                for (int mt = 0; mt < 2; ++mt)
                    Oacc[mt][nc] = __builtin_amdgcn_mfma_f32_16x16x32_bf16(
                        pa[mt][hf], vf[nc * 2 + hf], Oacc[mt][nc], 0, 0, 0);
        __builtin_amdgcn_s_setprio(0);
    }

    // ---- epilogue: 4-way combine of l and O, scale, store ----
    __syncthreads();                         // loop done: Ps region reusable soon
    if (quad == 0) {
        Lc[wid * 32 + l15]      = l_s[0];
        Lc[wid * 32 + 16 + l15] = l_s[1];
    }
    __syncthreads();
    float inv[2];
    #pragma unroll
    for (int nt = 0; nt < 2; ++nt) {
        const int off = nt * 16 + l15;
        inv[nt] = 1.0f / (Lc[off] + Lc[32 + off] + Lc[64 + off] + Lc[96 + off]);
    }
    float iw[2][4];
    #pragma unroll
    for (int mt = 0; mt < 2; ++mt)
        #pragma unroll
        for (int r = 0; r < 4; ++r)
            iw[mt][r] = __shfl(inv[mt], 4 * quad + r);

    float* Om = (wid & 1) ? Os1 : Os0;
    if (wid < 2) {
        #pragma unroll
        for (int mt = 0; mt < 2; ++mt)
            #pragma unroll
            for (int nc = 0; nc < 4; ++nc) {
                float4 o;
                o.x = Oacc[mt][nc][0] * iw[mt][0];
                o.y = Oacc[mt][nc][1] * iw[mt][1];
                o.z = Oacc[mt][nc][2] * iw[mt][2];
                o.w = Oacc[mt][nc][3] * iw[mt][3];
                *(float4*)&Om[(nc * 16 + l15) * 36 + mt * 16 + quad * 4] = o;
            }
    }
    __syncthreads();
    if (wid >= 2) {
        #pragma unroll
        for (int mt = 0; mt < 2; ++mt)
            #pragma unroll
            for (int nc = 0; nc < 4; ++nc) {
                float* p = &Om[(nc * 16 + l15) * 36 + mt * 16 + quad * 4];
                p[0] += Oacc[mt][nc][0] * iw[mt][0];
                p[1] += Oacc[mt][nc][1] * iw[mt][1];
                p[2] += Oacc[mt][nc][2] * iw[mt][2];
                p[3] += Oacc[mt][nc][3] * iw[mt][3];
            }
    }
    __syncthreads();
    #pragma unroll
    for (int ch = 0; ch < 2; ++ch) {
        int idx = tid + ch * 256;           // 0..511
        int c = idx >> 3, tch = idx & 7;
        f32x4 o0 = *(const f32x4*)&Os0[c * 36 + tch * 4];
        f32x4 o1 = *(const f32x4*)&Os1[c * 36 + tch * 4];
        f32x4 o = o0 + o1;
        *(f32x4*)(out + obase + (long)c * TSEQ + t0 + tch * 4) = o;
    }
}

extern "C" void kernel_launch(void* const* d_in, const int* in_sizes, int n_in,
                              void* d_out, int out_size, void* d_ws, size_t ws_size,
                              hipStream_t stream) {
    const float* qkv  = (const float*)d_in[0];
    const int*   mask = (const int*)d_in[1];
    float*       out  = (float*)d_out;
    short*       ws   = (short*)d_ws;       // needs 24 MiB
    prep_kernel<<<dim3(3072), dim3(256), 0, stream>>>(qkv, ws);
    attn_kernel<<<dim3(2048), dim3(256), 0, stream>>>(ws, mask, out);
}

// Round 5
// 137.948 us; speedup vs baseline: 2.9613x; 1.0231x over previous
//
#include <hip/hip_runtime.h>
#include <float.h>

// QKV attention, qkv [2,3072,2048] f32, mask [2,1,2048] i32, out [2,1024,2048] f32.
// R5: 32x32x16 MFMA + fully in-register P (T12 pattern).
// Swapped QK (D = K*Q^T) makes col=lane&31 = t, so each lane holds half the
// P-column of ONE t; lanes l / l+32 hold complementary s-halves. P -> PV
// A-fragment is 16 v_cvt_pk_bf16_f32 + 8 v_permlane32_swap_b32 per iter:
// the LDS P round-trip (8 ds_write + 4 ds_read + swizzle + 3.4M bank-conflict
// cycles + 48 pkbf ops) is GONE. Mask via MFMA C-init bias (free). Row-sum is
// in-lane + one shfl_xor(32) at epilogue. Loop LDS = 8KB bias only.
// Prep: Q -> [t][c] (pre-scaled 1/8*log2e); K,V -> 32x32-frag-major; V path
// now uses the same coalesced LDS-transpose loader as Q/K.

typedef __attribute__((ext_vector_type(8))) short bf16x8;
typedef __attribute__((ext_vector_type(4))) float f32x4;
typedef __attribute__((ext_vector_type(16))) float f32x16;

#define TSEQ 2048
#define QT_OFF 0L
#define KF_OFF 4194304L
#define VF_OFF 8388608L

#if __has_builtin(__builtin_amdgcn_exp2f)
#define EXPFN(x) __builtin_amdgcn_exp2f(x)
#define SM_SCALE (0.125f * 1.44269504088896f)
#else
#define EXPFN(x) __expf(x)
#define SM_SCALE 0.125f
#endif

__device__ inline short f2bf(float x) {
    union { float f; unsigned u; } un; un.f = x;
    unsigned r = un.u + 0x7fffu + ((un.u >> 16) & 1u);  // RNE
    return (short)(r >> 16);
}

// pack two f32 -> [bf16(lo) | bf16(hi)<<16], single HW op
__device__ inline unsigned cvtpk(float lo, float hi) {
    unsigned r;
    asm("v_cvt_pk_bf16_f32 %0, %1, %2" : "=v"(r) : "v"(lo), "v"(hi));
    return r;
}

// swap a's lanes 32-63 with b's lanes 0-31 (register-only cross-half exchange)
__device__ inline void pl32swap(unsigned &a, unsigned &b) {
    asm volatile("v_permlane32_swap_b32 %0, %1" : "+v"(a), "+v"(b));
}

// ---------------- pre-pass: convert + reorder ----------------
// 3072 blocks: tpe = job>>10 (0=Q,1=K,2=V), 1024 each: bh = 0..31, tt = 0..31.
// All types share one coalesced 64x64 f32 tile load into padded LDS.
__global__ __launch_bounds__(256) void prep_kernel(
    const float* __restrict__ qkv, short* __restrict__ ws)
{
    const int tid = threadIdx.x;
    const int job = blockIdx.x;
    const int tpe  = job >> 10;          // 0=Q 1=K 2=V
    const int rest = job & 1023;
    const int bh = rest & 31, tt = rest >> 5;
    const int b = bh >> 4, h = bh & 15;

    __shared__ float Ls[64 * 65];        // [row][col] = [c][t or s]
    const float* src = qkv + (long)b * 6291456
        + ((long)(tpe * 1024 + h * 64)) * TSEQ + tt * 64;
    #pragma unroll
    for (int ch = 0; ch < 4; ++ch) {
        int idx = tid + ch * 256;
        int c = idx >> 4, tch = idx & 15;
        float4 v = *(const float4*)(src + (long)c * TSEQ + tch * 4);
        float* L = &Ls[c * 65 + tch * 4];
        L[0] = v.x; L[1] = v.y; L[2] = v.z; L[3] = v.w;
    }
    __syncthreads();

    if (tpe == 0) {
        // Q -> [t][c], scaled
        short* dst = ws + QT_OFF + ((long)bh * TSEQ + tt * 64) * 64;
        #pragma unroll
        for (int ch = 0; ch < 2; ++ch) {
            int idx = tid + ch * 256;
            int t = idx >> 3, cch = idx & 7;
            bf16x8 o;
            #pragma unroll
            for (int j = 0; j < 8; ++j)
                o[j] = f2bf(Ls[(cch * 8 + j) * 65 + t] * SM_SCALE);
            *(bf16x8*)(dst + (long)t * 64 + cch * 8) = o;
        }
    } else if (tpe == 1) {
        // K 32x32-frag-major: f = st*4+kk, lane:
        //   K[s = tt*64 + st*32 + (lane&31)][c = kk*16 + (lane>>5)*8 + j]
        short* dst = ws + KF_OFF + (long)(bh * 32 + tt) * 4096;
        #pragma unroll
        for (int ch = 0; ch < 2; ++ch) {
            int u = tid + ch * 256;             // 0..511
            int f = u >> 6, lane = u & 63;
            int st = f >> 2, kk = f & 3;
            int l31 = lane & 31, H = lane >> 5;
            bf16x8 o;
            #pragma unroll
            for (int j = 0; j < 8; ++j)
                o[j] = f2bf(Ls[(kk * 16 + H * 8 + j) * 65 + st * 32 + l31]);
            *(bf16x8*)(dst + f * 512 + lane * 8) = o;
        }
    } else {
        // V 32x32-frag-major: f = ct*4+kk, lane:
        //   V[c = ct*32 + (lane&31)][s = tt*64 + kk*16 + (lane>>5)*8 + j]
        short* dst = ws + VF_OFF + (long)(bh * 32 + tt) * 4096;
        #pragma unroll
        for (int ch = 0; ch < 2; ++ch) {
            int u = tid + ch * 256;             // 0..511
            int f = u >> 6, lane = u & 63;
            int ct = f >> 2, kk = f & 3;
            int l31 = lane & 31, H = lane >> 5;
            bf16x8 o;
            #pragma unroll
            for (int j = 0; j < 8; ++j)
                o[j] = f2bf(Ls[(ct * 32 + l31) * 65 + kk * 16 + H * 8 + j]);
            *(bf16x8*)(dst + f * 512 + lane * 8) = o;
        }
    }
}

// ---------------- main attention (64 q/block, 4 waves = 2q x 2s, no loop barriers) ----------------
__global__ __launch_bounds__(256, 4) void attn_kernel(
    const short* __restrict__ wsp, const int* __restrict__ mask,
    float* __restrict__ out)
{
    __shared__ __align__(16) char smem[17920];
    float* mbf = (float*)smem;               // loop: 8KB bias (0 valid / -1e30 masked)
    float* Os  = (float*)smem;               // epilogue: [64][68] f32 (mbf dead)
    float* Lc  = (float*)(smem + 17408);     // 128 f32 l-combine

    const int tid  = threadIdx.x;
    const int lane = tid & 63, wid = tid >> 6;      // wid 0..3
    const int l31  = lane & 31, H = lane >> 5;
    const int wq   = wid & 1,  wss = wid >> 1;      // q-subtile / s-half

    const int blk  = blockIdx.x;             // 0..1023
    const int head = blk & 31;               // same-head blocks -> same XCD
    const int qt   = blk >> 5;               // 0..31
    const int b    = head >> 4, h = head & 15;
    const int t0   = qt * 64;
    const int tw   = t0 + wq * 32;           // this wave's 32 q-rows

    const short* QT = wsp + QT_OFF + (long)head * 131072;   // [t][c]
    const short* KF = wsp + KF_OFF + (long)head * 131072 + lane * 8;
    const short* VF = wsp + VF_OFF + (long)head * 131072 + lane * 8;
    const long obase = ((long)b * 1024 + h * 64) * TSEQ;

    for (int i = tid; i < TSEQ; i += 256)
        mbf[i] = (mask[b * TSEQ + i] != 0) ? 0.0f : -1e30f;
    __syncthreads();

    // Q B-frags: qb[kk]: t = tw+l31, c = kk*16 + H*8 + j
    bf16x8 qb[4];
    #pragma unroll
    for (int kk = 0; kk < 4; ++kk)
        qb[kk] = *(const bf16x8*)(QT + (long)(tw + l31) * 64 + kk * 16 + H * 8);
    const bool qv = (mbf[tw + l31] != 0.0f);     // q-row masked -> uniform P=1

    float l_s = 0.0f;
    f32x16 Oacc[2];
    #pragma unroll
    for (int ct = 0; ct < 2; ++ct)
        #pragma unroll
        for (int r = 0; r < 16; ++r) Oacc[ct][r] = 0.0f;

    // s-halves interleaved: wave wss does tiles wss, wss+2, ... (16 tiles of 64 s)
    for (int i = 0; i < 16; ++i) {
        const int it = wss + i * 2;

        // K A-frags (8 coalesced 1KB wave loads, L2-resident)
        const short* kp = KF + (long)it * 4096;
        bf16x8 kc[8];
        #pragma unroll
        for (int f = 0; f < 8; ++f)
            kc[f] = *(const bf16x8*)(kp + f * 512);

        // bias C-init: row s = (r&3) + 8*(r>>2) + 4H (+ st*32); 4x b128 per tile,
        // only 2 distinct addrs per wave -> broadcast, conflict-free
        f32x16 Sacc[2];
        #pragma unroll
        for (int st = 0; st < 2; ++st)
            #pragma unroll
            for (int g = 0; g < 4; ++g) {
                f32x4 b4 = *(const f32x4*)&mbf[it * 64 + st * 32 + g * 8 + H * 4];
                Sacc[st][4 * g + 0] = b4[0];
                Sacc[st][4 * g + 1] = b4[1];
                Sacc[st][4 * g + 2] = b4[2];
                Sacc[st][4 * g + 3] = b4[3];
            }

        // S^T = K Q^T + bias  (D[s][t]: col=lane&31=t, row=s pattern)
        __builtin_amdgcn_s_setprio(1);
        #pragma unroll
        for (int st = 0; st < 2; ++st)
            #pragma unroll
            for (int kk = 0; kk < 4; ++kk)
                Sacc[st] = __builtin_amdgcn_mfma_f32_32x32x16_bf16(
                    kc[st * 4 + kk], qb[kk], Sacc[st], 0, 0, 0);
        __builtin_amdgcn_s_setprio(0);

        // V B-frags (issued before softmax VALU -> latency hidden under it)
        const short* vp = VF + (long)it * 4096;
        bf16x8 vf[8];
        #pragma unroll
        for (int f = 0; f < 8; ++f)
            vf[f] = *(const bf16x8*)(vp + f * 512);

        // fixed-max softmax, fully in-register; pack to PV A-frags via
        // cvt_pk + permlane32_swap (lane l <-> l+32 complementary s-halves)
        bf16x8 pa[4];
        float ls = 0.0f;
        #pragma unroll
        for (int st = 0; st < 2; ++st) {
            #pragma unroll
            for (int r = 0; r < 16; ++r) {
                float e = EXPFN(Sacc[st][r]);
                float pv = qv ? 1.0f : e;
                ls += pv;
                Sacc[st][r] = pv;
            }
            unsigned w0[4], w1[4];   // w?[q]: s' = q*8 + 4H + {0,1}/{2,3}
            #pragma unroll
            for (int q = 0; q < 4; ++q) {
                w0[q] = cvtpk(Sacc[st][4 * q + 0], Sacc[st][4 * q + 1]);
                w1[q] = cvtpk(Sacc[st][4 * q + 2], Sacc[st][4 * q + 3]);
            }
            #pragma unroll
            for (int kl = 0; kl < 2; ++kl) {
                unsigned a0 = w0[kl * 2], b0 = w0[kl * 2 + 1];
                unsigned a1 = w1[kl * 2], b1 = w1[kl * 2 + 1];
                pl32swap(a0, b0);
                pl32swap(a1, b1);
                union { unsigned u[4]; bf16x8 v; } cv;
                cv.u[0] = a0; cv.u[1] = a1; cv.u[2] = b0; cv.u[3] = b1;
                pa[st * 2 + kl] = cv.v;   // s = (st*2+kl)*16 + H*8 + {0..7}
            }
        }
        l_s += ls;

        // O += P V^T  (D[t][c]: col=lane&31=c, row=t pattern)
        __builtin_amdgcn_s_setprio(1);
        #pragma unroll
        for (int ct = 0; ct < 2; ++ct)
            #pragma unroll
            for (int kk = 0; kk < 4; ++kk)
                Oacc[ct] = __builtin_amdgcn_mfma_f32_32x32x16_bf16(
                    pa[kk], vf[ct * 4 + kk], Oacc[ct], 0, 0, 0);
        __builtin_amdgcn_s_setprio(0);
    }

    // ---- epilogue: combine lane-halves + s-halves, scale, store ----
    __syncthreads();                         // loop done; mbf dead
    l_s += __shfl_xor(l_s, 32);              // full row sum for t = tw + l31
    if (lane < 32) Lc[wid * 32 + l31] = l_s;
    __syncthreads();
    const float inv = 1.0f / (l_s + Lc[(wid ^ 2) * 32 + l31]);
    float iw[16];
    #pragma unroll
    for (int r = 0; r < 16; ++r)
        iw[r] = __shfl(inv, (r & 3) + 8 * (r >> 2) + 4 * H);

    if (wss == 0) {
        #pragma unroll
        for (int ct = 0; ct < 2; ++ct) {
            const int c = ct * 32 + l31;
            #pragma unroll
            for (int g = 0; g < 4; ++g) {
                float4 o;
                o.x = Oacc[ct][4 * g + 0] * iw[4 * g + 0];
                o.y = Oacc[ct][4 * g + 1] * iw[4 * g + 1];
                o.z = Oacc[ct][4 * g + 2] * iw[4 * g + 2];
                o.w = Oacc[ct][4 * g + 3] * iw[4 * g + 3];
                *(float4*)&Os[c * 68 + wq * 32 + g * 8 + H * 4] = o;
            }
        }
    }
    __syncthreads();
    if (wss == 1) {
        #pragma unroll
        for (int ct = 0; ct < 2; ++ct) {
            const int c = ct * 32 + l31;
            #pragma unroll
            for (int g = 0; g < 4; ++g) {
                float* p = &Os[c * 68 + wq * 32 + g * 8 + H * 4];
                p[0] += Oacc[ct][4 * g + 0] * iw[4 * g + 0];
                p[1] += Oacc[ct][4 * g + 1] * iw[4 * g + 1];
                p[2] += Oacc[ct][4 * g + 2] * iw[4 * g + 2];
                p[3] += Oacc[ct][4 * g + 3] * iw[4 * g + 3];
            }
        }
    }
    __syncthreads();
    #pragma unroll
    for (int ch = 0; ch < 4; ++ch) {
        int idx = tid + ch * 256;           // 0..1023
        int c = idx >> 4, tch = idx & 15;
        *(float4*)(out + obase + (long)c * TSEQ + t0 + tch * 4) =
            *(const float4*)&Os[c * 68 + tch * 4];
    }
}

extern "C" void kernel_launch(void* const* d_in, const int* in_sizes, int n_in,
                              void* d_out, int out_size, void* d_ws, size_t ws_size,
                              hipStream_t stream) {
    const float* qkv  = (const float*)d_in[0];
    const int*   mask = (const int*)d_in[1];
    float*       out  = (float*)d_out;
    short*       ws   = (short*)d_ws;       // needs 24 MiB
    prep_kernel<<<dim3(3072), dim3(256), 0, stream>>>(qkv, ws);
    attn_kernel<<<dim3(1024), dim3(256), 0, stream>>>(ws, mask, out);
}

// Round 7
// 137.184 us; speedup vs baseline: 2.9778x; 1.0056x over previous
//
#include <hip/hip_runtime.h>
#include <float.h>

// QKV attention, qkv [2,3072,2048] f32, mask [2,1,2048] i32, out [2,1024,2048] f32.
// R6: register-occupancy fix. R2-R5 were all pinned at ~10.5 waves/CU =
// 2048-reg pool / ~192 true regs per wave (VGPR_Count=64 is arch-only; AGPR
// accumulators share the gfx950 unified file) -- which is why grid/LDS/VALU
// changes never moved dur_us: too few waves to cover the ~300cyc L2 K/V
// latency. This round processes 32-s SUBTILES (kc 4 frags, vf 4 frags,
// Sacc f32x16 x1 instead of x2) cutting peak live regs ~190 -> ~112, raising
// the HW cap to ~18 waves/CU (grid supplies 16). Same math, same bytes, same
// in-register softmax (cvt_pk_bf16 + permlane32_swap) as R5.
// Prep unchanged from R5: Q -> [t][c] (pre-scaled 1/8*log2e); K,V ->
// 32x32-frag-major so each frag is one coalesced 1KB wave load.
// (R6 resubmit: previous bench failed on container acquisition, not kernel.)

typedef __attribute__((ext_vector_type(8))) short bf16x8;
typedef __attribute__((ext_vector_type(4))) float f32x4;
typedef __attribute__((ext_vector_type(16))) float f32x16;

#define TSEQ 2048
#define QT_OFF 0L
#define KF_OFF 4194304L
#define VF_OFF 8388608L

#if __has_builtin(__builtin_amdgcn_exp2f)
#define EXPFN(x) __builtin_amdgcn_exp2f(x)
#define SM_SCALE (0.125f * 1.44269504088896f)
#else
#define EXPFN(x) __expf(x)
#define SM_SCALE 0.125f
#endif

__device__ inline short f2bf(float x) {
    union { float f; unsigned u; } un; un.f = x;
    unsigned r = un.u + 0x7fffu + ((un.u >> 16) & 1u);  // RNE
    return (short)(r >> 16);
}

// pack two f32 -> [bf16(lo) | bf16(hi)<<16], single HW op
__device__ inline unsigned cvtpk(float lo, float hi) {
    unsigned r;
    asm("v_cvt_pk_bf16_f32 %0, %1, %2" : "=v"(r) : "v"(lo), "v"(hi));
    return r;
}

// swap a's lanes 32-63 with b's lanes 0-31 (register-only cross-half exchange)
__device__ inline void pl32swap(unsigned &a, unsigned &b) {
    asm volatile("v_permlane32_swap_b32 %0, %1" : "+v"(a), "+v"(b));
}

// ---------------- pre-pass: convert + reorder ----------------
// 3072 blocks: tpe = job>>10 (0=Q,1=K,2=V), 1024 each: bh = 0..31, tt = 0..31.
// All types share one coalesced 64x64 f32 tile load into padded LDS.
__global__ __launch_bounds__(256) void prep_kernel(
    const float* __restrict__ qkv, short* __restrict__ ws)
{
    const int tid = threadIdx.x;
    const int job = blockIdx.x;
    const int tpe  = job >> 10;          // 0=Q 1=K 2=V
    const int rest = job & 1023;
    const int bh = rest & 31, tt = rest >> 5;
    const int b = bh >> 4, h = bh & 15;

    __shared__ float Ls[64 * 65];        // [row][col] = [c][t or s]
    const float* src = qkv + (long)b * 6291456
        + ((long)(tpe * 1024 + h * 64)) * TSEQ + tt * 64;
    #pragma unroll
    for (int ch = 0; ch < 4; ++ch) {
        int idx = tid + ch * 256;
        int c = idx >> 4, tch = idx & 15;
        float4 v = *(const float4*)(src + (long)c * TSEQ + tch * 4);
        float* L = &Ls[c * 65 + tch * 4];
        L[0] = v.x; L[1] = v.y; L[2] = v.z; L[3] = v.w;
    }
    __syncthreads();

    if (tpe == 0) {
        // Q -> [t][c], scaled
        short* dst = ws + QT_OFF + ((long)bh * TSEQ + tt * 64) * 64;
        #pragma unroll
        for (int ch = 0; ch < 2; ++ch) {
            int idx = tid + ch * 256;
            int t = idx >> 3, cch = idx & 7;
            bf16x8 o;
            #pragma unroll
            for (int j = 0; j < 8; ++j)
                o[j] = f2bf(Ls[(cch * 8 + j) * 65 + t] * SM_SCALE);
            *(bf16x8*)(dst + (long)t * 64 + cch * 8) = o;
        }
    } else if (tpe == 1) {
        // K 32x32-frag-major: f = st*4+kk, lane:
        //   K[s = tt*64 + st*32 + (lane&31)][c = kk*16 + (lane>>5)*8 + j]
        short* dst = ws + KF_OFF + (long)(bh * 32 + tt) * 4096;
        #pragma unroll
        for (int ch = 0; ch < 2; ++ch) {
            int u = tid + ch * 256;             // 0..511
            int f = u >> 6, lane = u & 63;
            int st = f >> 2, kk = f & 3;
            int l31 = lane & 31, H = lane >> 5;
            bf16x8 o;
            #pragma unroll
            for (int j = 0; j < 8; ++j)
                o[j] = f2bf(Ls[(kk * 16 + H * 8 + j) * 65 + st * 32 + l31]);
            *(bf16x8*)(dst + f * 512 + lane * 8) = o;
        }
    } else {
        // V 32x32-frag-major: f = ct*4+kk, lane:
        //   V[c = ct*32 + (lane&31)][s = tt*64 + kk*16 + (lane>>5)*8 + j]
        short* dst = ws + VF_OFF + (long)(bh * 32 + tt) * 4096;
        #pragma unroll
        for (int ch = 0; ch < 2; ++ch) {
            int u = tid + ch * 256;             // 0..511
            int f = u >> 6, lane = u & 63;
            int ct = f >> 2, kk = f & 3;
            int l31 = lane & 31, H = lane >> 5;
            bf16x8 o;
            #pragma unroll
            for (int j = 0; j < 8; ++j)
                o[j] = f2bf(Ls[(ct * 32 + l31) * 65 + kk * 16 + H * 8 + j]);
            *(bf16x8*)(dst + f * 512 + lane * 8) = o;
        }
    }
}

// ---------------- main attention (64 q/block, 4 waves = 2q x 2s, 32-s subtiles) ----------------
__global__ __launch_bounds__(256, 4) void attn_kernel(
    const short* __restrict__ wsp, const int* __restrict__ mask,
    float* __restrict__ out)
{
    __shared__ __align__(16) char smem[17920];
    float* mbf = (float*)smem;               // loop: 8KB bias (0 valid / -1e30 masked)
    float* Os  = (float*)smem;               // epilogue: [64][68] f32 (mbf dead)
    float* Lc  = (float*)(smem + 17408);     // 128 f32 l-combine

    const int tid  = threadIdx.x;
    const int lane = tid & 63, wid = tid >> 6;      // wid 0..3
    const int l31  = lane & 31, H = lane >> 5;
    const int wq   = wid & 1,  wss = wid >> 1;      // q-subtile / s-half

    const int blk  = blockIdx.x;             // 0..1023
    const int head = blk & 31;               // same-head blocks -> same XCD
    const int qt   = blk >> 5;               // 0..31
    const int b    = head >> 4, h = head & 15;
    const int t0   = qt * 64;
    const int tw   = t0 + wq * 32;           // this wave's 32 q-rows

    const short* QT = wsp + QT_OFF + (long)head * 131072;   // [t][c]
    const short* KF = wsp + KF_OFF + (long)head * 131072 + lane * 8;
    const short* VF = wsp + VF_OFF + (long)head * 131072 + lane * 8;
    const long obase = ((long)b * 1024 + h * 64) * TSEQ;

    for (int i = tid; i < TSEQ; i += 256)
        mbf[i] = (mask[b * TSEQ + i] != 0) ? 0.0f : -1e30f;
    __syncthreads();

    // Q B-frags: qb[kk]: t = tw+l31, c = kk*16 + H*8 + j
    bf16x8 qb[4];
    #pragma unroll
    for (int kk = 0; kk < 4; ++kk)
        qb[kk] = *(const bf16x8*)(QT + (long)(tw + l31) * 64 + kk * 16 + H * 8);
    const bool qv = (mbf[tw + l31] != 0.0f);     // q-row masked -> uniform P=1

    float l_s = 0.0f;
    f32x16 Oacc[2];
    #pragma unroll
    for (int ct = 0; ct < 2; ++ct)
        #pragma unroll
        for (int r = 0; r < 16; ++r) Oacc[ct][r] = 0.0f;

    // 64 subtiles of 32 s; wave wss takes ss = wss, wss+2, ... (32 subtiles)
    for (int j = 0; j < 32; ++j) {
        const int ss = wss + j * 2;

        // K A-frags for this subtile (4 coalesced 1KB wave loads, L2-resident)
        const short* kp = KF + ss * 2048;
        bf16x8 kc[4];
        #pragma unroll
        for (int kk = 0; kk < 4; ++kk)
            kc[kk] = *(const bf16x8*)(kp + kk * 512);

        // V B-frags issued NOW: consumed only after softmax, so the compiler's
        // counted vmcnt leaves them in flight under the S-MFMA + exp VALU.
        const short* vp = VF + (ss >> 1) * 4096 + (ss & 1) * 1024;
        bf16x8 vf[4];
        #pragma unroll
        for (int ct = 0; ct < 2; ++ct)
            #pragma unroll
            for (int m = 0; m < 2; ++m)
                vf[ct * 2 + m] = *(const bf16x8*)(vp + ct * 2048 + m * 512);

        // bias C-init: reg r -> s-local = (r&3)+8*(r>>2)+4H; broadcast b128 reads
        f32x16 Sacc;
        #pragma unroll
        for (int g = 0; g < 4; ++g) {
            f32x4 b4 = *(const f32x4*)&mbf[ss * 32 + g * 8 + H * 4];
            Sacc[4 * g + 0] = b4[0];
            Sacc[4 * g + 1] = b4[1];
            Sacc[4 * g + 2] = b4[2];
            Sacc[4 * g + 3] = b4[3];
        }

        // S^T = K Q^T + bias  (D[s][t]: col=lane&31=t)
        __builtin_amdgcn_s_setprio(1);
        #pragma unroll
        for (int kk = 0; kk < 4; ++kk)
            Sacc = __builtin_amdgcn_mfma_f32_32x32x16_bf16(
                kc[kk], qb[kk], Sacc, 0, 0, 0);
        __builtin_amdgcn_s_setprio(0);

        // fixed-max softmax, in-register; pack to PV A-frags via
        // cvt_pk + permlane32_swap (lane l <-> l+32 complementary s-halves)
        float ls = 0.0f;
        #pragma unroll
        for (int r = 0; r < 16; ++r) {
            float e = EXPFN(Sacc[r]);
            float pv = qv ? 1.0f : e;
            ls += pv;
            Sacc[r] = pv;
        }
        l_s += ls;
        unsigned w0[4], w1[4];   // w?[q]: s' = q*8 + 4H + {0,1}/{2,3}
        #pragma unroll
        for (int q = 0; q < 4; ++q) {
            w0[q] = cvtpk(Sacc[4 * q + 0], Sacc[4 * q + 1]);
            w1[q] = cvtpk(Sacc[4 * q + 2], Sacc[4 * q + 3]);
        }
        bf16x8 pa[2];
        #pragma unroll
        for (int kl = 0; kl < 2; ++kl) {
            unsigned a0 = w0[kl * 2], b0 = w0[kl * 2 + 1];
            unsigned a1 = w1[kl * 2], b1 = w1[kl * 2 + 1];
            pl32swap(a0, b0);
            pl32swap(a1, b1);
            union { unsigned u[4]; bf16x8 v; } cv;
            cv.u[0] = a0; cv.u[1] = a1; cv.u[2] = b0; cv.u[3] = b1;
            pa[kl] = cv.v;   // s-local = kl*16 + H*8 + {0..7}
        }

        // O += P V^T  (D[t][c]: col=lane&31=c)
        __builtin_amdgcn_s_setprio(1);
        #pragma unroll
        for (int ct = 0; ct < 2; ++ct)
            #pragma unroll
            for (int m = 0; m < 2; ++m)
                Oacc[ct] = __builtin_amdgcn_mfma_f32_32x32x16_bf16(
                    pa[m], vf[ct * 2 + m], Oacc[ct], 0, 0, 0);
        __builtin_amdgcn_s_setprio(0);
    }

    // ---- epilogue: combine lane-halves + s-halves, scale, store ----
    __syncthreads();                         // loop done; mbf dead
    l_s += __shfl_xor(l_s, 32);              // full row sum for t = tw + l31
    if (lane < 32) Lc[wid * 32 + l31] = l_s;
    __syncthreads();
    const float inv = 1.0f / (l_s + Lc[(wid ^ 2) * 32 + l31]);
    float iw[16];
    #pragma unroll
    for (int r = 0; r < 16; ++r)
        iw[r] = __shfl(inv, (r & 3) + 8 * (r >> 2) + 4 * H);

    if (wss == 0) {
        #pragma unroll
        for (int ct = 0; ct < 2; ++ct) {
            const int c = ct * 32 + l31;
            #pragma unroll
            for (int g = 0; g < 4; ++g) {
                float4 o;
                o.x = Oacc[ct][4 * g + 0] * iw[4 * g + 0];
                o.y = Oacc[ct][4 * g + 1] * iw[4 * g + 1];
                o.z = Oacc[ct][4 * g + 2] * iw[4 * g + 2];
                o.w = Oacc[ct][4 * g + 3] * iw[4 * g + 3];
                *(float4*)&Os[c * 68 + wq * 32 + g * 8 + H * 4] = o;
            }
        }
    }
    __syncthreads();
    if (wss == 1) {
        #pragma unroll
        for (int ct = 0; ct < 2; ++ct) {
            const int c = ct * 32 + l31;
            #pragma unroll
            for (int g = 0; g < 4; ++g) {
                float* p = &Os[c * 68 + wq * 32 + g * 8 + H * 4];
                p[0] += Oacc[ct][4 * g + 0] * iw[4 * g + 0];
                p[1] += Oacc[ct][4 * g + 1] * iw[4 * g + 1];
                p[2] += Oacc[ct][4 * g + 2] * iw[4 * g + 2];
                p[3] += Oacc[ct][4 * g + 3] * iw[4 * g + 3];
            }
        }
    }
    __syncthreads();
    #pragma unroll
    for (int ch = 0; ch < 4; ++ch) {
        int idx = tid + ch * 256;           // 0..1023
        int c = idx >> 4, tch = idx & 15;
        *(float4*)(out + obase + (long)c * TSEQ + t0 + tch * 4) =
            *(const float4*)&Os[c * 68 + tch * 4];
    }
}

extern "C" void kernel_launch(void* const* d_in, const int* in_sizes, int n_in,
                              void* d_out, int out_size, void* d_ws, size_t ws_size,
                              hipStream_t stream) {
    const float* qkv  = (const float*)d_in[0];
    const int*   mask = (const int*)d_in[1];
    float*       out  = (float*)d_out;
    short*       ws   = (short*)d_ws;       // needs 24 MiB
    prep_kernel<<<dim3(3072), dim3(256), 0, stream>>>(qkv, ws);
    attn_kernel<<<dim3(1024), dim3(256), 0, stream>>>(ws, mask, out);
}

// Round 8
// 134.972 us; speedup vs baseline: 3.0266x; 1.0164x over previous
//
#include <hip/hip_runtime.h>
#include <float.h>

// QKV attention, qkv [2,3072,2048] f32, mask [2,1,2048] i32, out [2,1024,2048] f32.
// R8: 1-deep K software pipeline on top of R6. Four rounds (R2/R4/R5/R6)
// proved nominal-occupancy changes do nothing (resident waves pinned ~9-10/CU)
// while ILP changes moved dur_us; the remaining 2x-over-floor gap is the
// ~300cyc L2 latency of kc, consumed immediately after issue each subtile.
// Fix: paired A/B bodies (static register names, rule-#20-safe) load kc(j+1)
// before computing step j -> every K load covered by a full step (~450cyc of
// MFMA+softmax+PV). V stays in-step (already covered by S-MFMA+softmax).
// launch_bounds (256,3): +16 live regs must NOT spill (R3 lesson) -- spills
// are catastrophic, nominal TLP loss is measured-free.
// Math identical to R6: 32x32x16 MFMA, in-register softmax via
// v_cvt_pk_bf16_f32 + v_permlane32_swap_b32, mask as MFMA C-init bias.

typedef __attribute__((ext_vector_type(8))) short bf16x8;
typedef __attribute__((ext_vector_type(4))) float f32x4;
typedef __attribute__((ext_vector_type(16))) float f32x16;

#define TSEQ 2048
#define QT_OFF 0L
#define KF_OFF 4194304L
#define VF_OFF 8388608L

#if __has_builtin(__builtin_amdgcn_exp2f)
#define EXPFN(x) __builtin_amdgcn_exp2f(x)
#define SM_SCALE (0.125f * 1.44269504088896f)
#else
#define EXPFN(x) __expf(x)
#define SM_SCALE 0.125f
#endif

__device__ inline short f2bf(float x) {
    union { float f; unsigned u; } un; un.f = x;
    unsigned r = un.u + 0x7fffu + ((un.u >> 16) & 1u);  // RNE
    return (short)(r >> 16);
}

// pack two f32 -> [bf16(lo) | bf16(hi)<<16], single HW op
__device__ inline unsigned cvtpk(float lo, float hi) {
    unsigned r;
    asm("v_cvt_pk_bf16_f32 %0, %1, %2" : "=v"(r) : "v"(lo), "v"(hi));
    return r;
}

// swap a's lanes 32-63 with b's lanes 0-31 (register-only cross-half exchange)
__device__ inline void pl32swap(unsigned &a, unsigned &b) {
    asm volatile("v_permlane32_swap_b32 %0, %1" : "+v"(a), "+v"(b));
}

// ---------------- pre-pass: convert + reorder ----------------
// 3072 blocks: tpe = job>>10 (0=Q,1=K,2=V), 1024 each: bh = 0..31, tt = 0..31.
// All types share one coalesced 64x64 f32 tile load into padded LDS.
__global__ __launch_bounds__(256) void prep_kernel(
    const float* __restrict__ qkv, short* __restrict__ ws)
{
    const int tid = threadIdx.x;
    const int job = blockIdx.x;
    const int tpe  = job >> 10;          // 0=Q 1=K 2=V
    const int rest = job & 1023;
    const int bh = rest & 31, tt = rest >> 5;
    const int b = bh >> 4, h = bh & 15;

    __shared__ float Ls[64 * 65];        // [row][col] = [c][t or s]
    const float* src = qkv + (long)b * 6291456
        + ((long)(tpe * 1024 + h * 64)) * TSEQ + tt * 64;
    #pragma unroll
    for (int ch = 0; ch < 4; ++ch) {
        int idx = tid + ch * 256;
        int c = idx >> 4, tch = idx & 15;
        float4 v = *(const float4*)(src + (long)c * TSEQ + tch * 4);
        float* L = &Ls[c * 65 + tch * 4];
        L[0] = v.x; L[1] = v.y; L[2] = v.z; L[3] = v.w;
    }
    __syncthreads();

    if (tpe == 0) {
        // Q -> [t][c], scaled
        short* dst = ws + QT_OFF + ((long)bh * TSEQ + tt * 64) * 64;
        #pragma unroll
        for (int ch = 0; ch < 2; ++ch) {
            int idx = tid + ch * 256;
            int t = idx >> 3, cch = idx & 7;
            bf16x8 o;
            #pragma unroll
            for (int j = 0; j < 8; ++j)
                o[j] = f2bf(Ls[(cch * 8 + j) * 65 + t] * SM_SCALE);
            *(bf16x8*)(dst + (long)t * 64 + cch * 8) = o;
        }
    } else if (tpe == 1) {
        // K 32x32-frag-major: f = st*4+kk, lane:
        //   K[s = tt*64 + st*32 + (lane&31)][c = kk*16 + (lane>>5)*8 + j]
        short* dst = ws + KF_OFF + (long)(bh * 32 + tt) * 4096;
        #pragma unroll
        for (int ch = 0; ch < 2; ++ch) {
            int u = tid + ch * 256;             // 0..511
            int f = u >> 6, lane = u & 63;
            int st = f >> 2, kk = f & 3;
            int l31 = lane & 31, H = lane >> 5;
            bf16x8 o;
            #pragma unroll
            for (int j = 0; j < 8; ++j)
                o[j] = f2bf(Ls[(kk * 16 + H * 8 + j) * 65 + st * 32 + l31]);
            *(bf16x8*)(dst + f * 512 + lane * 8) = o;
        }
    } else {
        // V 32x32-frag-major: f = ct*4+kk, lane:
        //   V[c = ct*32 + (lane&31)][s = tt*64 + kk*16 + (lane>>5)*8 + j]
        short* dst = ws + VF_OFF + (long)(bh * 32 + tt) * 4096;
        #pragma unroll
        for (int ch = 0; ch < 2; ++ch) {
            int u = tid + ch * 256;             // 0..511
            int f = u >> 6, lane = u & 63;
            int ct = f >> 2, kk = f & 3;
            int l31 = lane & 31, H = lane >> 5;
            bf16x8 o;
            #pragma unroll
            for (int j = 0; j < 8; ++j)
                o[j] = f2bf(Ls[(ct * 32 + l31) * 65 + kk * 16 + H * 8 + j]);
            *(bf16x8*)(dst + f * 512 + lane * 8) = o;
        }
    }
}

// load the 4 K A-frags of subtile ss (4 coalesced 1KB wave loads)
__device__ __forceinline__ void load_k(const short* KF, int ss, bf16x8 (&kc)[4]) {
    const short* kp = KF + ss * 2048;
    #pragma unroll
    for (int kk = 0; kk < 4; ++kk)
        kc[kk] = *(const bf16x8*)(kp + kk * 512);
}

// one 32-s subtile step: vf load (in-step, covered by S-MFMA+softmax),
// bias C-init, S = K Q^T + bias, in-register softmax -> pa, O += P V^T
__device__ __forceinline__ void step(
    int ss, const float* mbf, int H, bool qv,
    const bf16x8 (&kc)[4], const bf16x8 (&qb)[4], const short* VF,
    f32x16 (&Oacc)[2], float &l_s)
{
    // V B-frags: issued first, consumed only after softmax
    const short* vp = VF + (ss >> 1) * 4096 + (ss & 1) * 1024;
    bf16x8 vf[4];
    #pragma unroll
    for (int ct = 0; ct < 2; ++ct)
        #pragma unroll
        for (int m = 0; m < 2; ++m)
            vf[ct * 2 + m] = *(const bf16x8*)(vp + ct * 2048 + m * 512);

    // bias C-init: reg r -> s-local = (r&3)+8*(r>>2)+4H; broadcast b128 reads
    f32x16 Sacc;
    #pragma unroll
    for (int g = 0; g < 4; ++g) {
        f32x4 b4 = *(const f32x4*)&mbf[ss * 32 + g * 8 + H * 4];
        Sacc[4 * g + 0] = b4[0];
        Sacc[4 * g + 1] = b4[1];
        Sacc[4 * g + 2] = b4[2];
        Sacc[4 * g + 3] = b4[3];
    }

    // S^T = K Q^T + bias  (D[s][t]: col=lane&31=t)
    __builtin_amdgcn_s_setprio(1);
    #pragma unroll
    for (int kk = 0; kk < 4; ++kk)
        Sacc = __builtin_amdgcn_mfma_f32_32x32x16_bf16(
            kc[kk], qb[kk], Sacc, 0, 0, 0);
    __builtin_amdgcn_s_setprio(0);

    // fixed-max softmax, in-register; pack to PV A-frags via
    // cvt_pk + permlane32_swap (lane l <-> l+32 complementary s-halves)
    float ls = 0.0f;
    #pragma unroll
    for (int r = 0; r < 16; ++r) {
        float e = EXPFN(Sacc[r]);
        float pv = qv ? 1.0f : e;
        ls += pv;
        Sacc[r] = pv;
    }
    l_s += ls;
    unsigned w0[4], w1[4];   // w?[q]: s' = q*8 + 4H + {0,1}/{2,3}
    #pragma unroll
    for (int q = 0; q < 4; ++q) {
        w0[q] = cvtpk(Sacc[4 * q + 0], Sacc[4 * q + 1]);
        w1[q] = cvtpk(Sacc[4 * q + 2], Sacc[4 * q + 3]);
    }
    bf16x8 pa[2];
    #pragma unroll
    for (int kl = 0; kl < 2; ++kl) {
        unsigned a0 = w0[kl * 2], b0 = w0[kl * 2 + 1];
        unsigned a1 = w1[kl * 2], b1 = w1[kl * 2 + 1];
        pl32swap(a0, b0);
        pl32swap(a1, b1);
        union { unsigned u[4]; bf16x8 v; } cv;
        cv.u[0] = a0; cv.u[1] = a1; cv.u[2] = b0; cv.u[3] = b1;
        pa[kl] = cv.v;   // s-local = kl*16 + H*8 + {0..7}
    }

    // O += P V^T  (D[t][c]: col=lane&31=c)
    __builtin_amdgcn_s_setprio(1);
    #pragma unroll
    for (int ct = 0; ct < 2; ++ct)
        #pragma unroll
        for (int m = 0; m < 2; ++m)
            Oacc[ct] = __builtin_amdgcn_mfma_f32_32x32x16_bf16(
                pa[m], vf[ct * 2 + m], Oacc[ct], 0, 0, 0);
    __builtin_amdgcn_s_setprio(0);
}

// ---------------- main attention (64 q/block, 4 waves = 2q x 2s, K-pipelined) ----------------
__global__ __launch_bounds__(256, 3) void attn_kernel(
    const short* __restrict__ wsp, const int* __restrict__ mask,
    float* __restrict__ out)
{
    __shared__ __align__(16) char smem[17920];
    float* mbf = (float*)smem;               // loop: 8KB bias (0 valid / -1e30 masked)
    float* Os  = (float*)smem;               // epilogue: [64][68] f32 (mbf dead)
    float* Lc  = (float*)(smem + 17408);     // 128 f32 l-combine

    const int tid  = threadIdx.x;
    const int lane = tid & 63, wid = tid >> 6;      // wid 0..3
    const int l31  = lane & 31, H = lane >> 5;
    const int wq   = wid & 1,  wss = wid >> 1;      // q-subtile / s-half

    const int blk  = blockIdx.x;             // 0..1023
    const int head = blk & 31;               // same-head blocks -> same XCD
    const int qt   = blk >> 5;               // 0..31
    const int b    = head >> 4, h = head & 15;
    const int t0   = qt * 64;
    const int tw   = t0 + wq * 32;           // this wave's 32 q-rows

    const short* QT = wsp + QT_OFF + (long)head * 131072;   // [t][c]
    const short* KF = wsp + KF_OFF + (long)head * 131072 + lane * 8;
    const short* VF = wsp + VF_OFF + (long)head * 131072 + lane * 8;
    const long obase = ((long)b * 1024 + h * 64) * TSEQ;

    for (int i = tid; i < TSEQ; i += 256)
        mbf[i] = (mask[b * TSEQ + i] != 0) ? 0.0f : -1e30f;
    __syncthreads();

    // Q B-frags: qb[kk]: t = tw+l31, c = kk*16 + H*8 + j
    bf16x8 qb[4];
    #pragma unroll
    for (int kk = 0; kk < 4; ++kk)
        qb[kk] = *(const bf16x8*)(QT + (long)(tw + l31) * 64 + kk * 16 + H * 8);
    const bool qv = (mbf[tw + l31] != 0.0f);     // q-row masked -> uniform P=1

    float l_s = 0.0f;
    f32x16 Oacc[2];
    #pragma unroll
    for (int ct = 0; ct < 2; ++ct)
        #pragma unroll
        for (int r = 0; r < 16; ++r) Oacc[ct][r] = 0.0f;

    // wave processes subtiles ss = wss + 2*j, j = 0..31.
    // 1-deep K pipeline with static A/B buffers: kc(j+1) issued before step(j).
    bf16x8 kcA[4], kcB[4];
    load_k(KF, wss, kcA);                        // j = 0
    for (int jj = 0; jj < 15; ++jj) {
        const int jA = 2 * jj, jB = 2 * jj + 1;
        load_k(KF, wss + 2 * jB, kcB);           // j = jB
        step(wss + 2 * jA, mbf, H, qv, kcA, qb, VF, Oacc, l_s);
        load_k(KF, wss + 2 * (jB + 1), kcA);     // j = jB+1
        step(wss + 2 * jB, mbf, H, qv, kcB, qb, VF, Oacc, l_s);
    }
    load_k(KF, wss + 2 * 31, kcB);               // j = 31
    step(wss + 2 * 30, mbf, H, qv, kcA, qb, VF, Oacc, l_s);
    step(wss + 2 * 31, mbf, H, qv, kcB, qb, VF, Oacc, l_s);

    // ---- epilogue: combine lane-halves + s-halves, scale, store ----
    __syncthreads();                         // loop done; mbf dead
    l_s += __shfl_xor(l_s, 32);              // full row sum for t = tw + l31
    if (lane < 32) Lc[wid * 32 + l31] = l_s;
    __syncthreads();
    const float inv = 1.0f / (l_s + Lc[(wid ^ 2) * 32 + l31]);
    float iw[16];
    #pragma unroll
    for (int r = 0; r < 16; ++r)
        iw[r] = __shfl(inv, (r & 3) + 8 * (r >> 2) + 4 * H);

    if (wss == 0) {
        #pragma unroll
        for (int ct = 0; ct < 2; ++ct) {
            const int c = ct * 32 + l31;
            #pragma unroll
            for (int g = 0; g < 4; ++g) {
                float4 o;
                o.x = Oacc[ct][4 * g + 0] * iw[4 * g + 0];
                o.y = Oacc[ct][4 * g + 1] * iw[4 * g + 1];
                o.z = Oacc[ct][4 * g + 2] * iw[4 * g + 2];
                o.w = Oacc[ct][4 * g + 3] * iw[4 * g + 3];
                *(float4*)&Os[c * 68 + wq * 32 + g * 8 + H * 4] = o;
            }
        }
    }
    __syncthreads();
    if (wss == 1) {
        #pragma unroll
        for (int ct = 0; ct < 2; ++ct) {
            const int c = ct * 32 + l31;
            #pragma unroll
            for (int g = 0; g < 4; ++g) {
                float* p = &Os[c * 68 + wq * 32 + g * 8 + H * 4];
                p[0] += Oacc[ct][4 * g + 0] * iw[4 * g + 0];
                p[1] += Oacc[ct][4 * g + 1] * iw[4 * g + 1];
                p[2] += Oacc[ct][4 * g + 2] * iw[4 * g + 2];
                p[3] += Oacc[ct][4 * g + 3] * iw[4 * g + 3];
            }
        }
    }
    __syncthreads();
    #pragma unroll
    for (int ch = 0; ch < 4; ++ch) {
        int idx = tid + ch * 256;           // 0..1023
        int c = idx >> 4, tch = idx & 15;
        *(float4*)(out + obase + (long)c * TSEQ + t0 + tch * 4) =
            *(const float4*)&Os[c * 68 + tch * 4];
    }
}

extern "C" void kernel_launch(void* const* d_in, const int* in_sizes, int n_in,
                              void* d_out, int out_size, void* d_ws, size_t ws_size,
                              hipStream_t stream) {
    const float* qkv  = (const float*)d_in[0];
    const int*   mask = (const int*)d_in[1];
    float*       out  = (float*)d_out;
    short*       ws   = (short*)d_ws;       // needs 24 MiB
    prep_kernel<<<dim3(3072), dim3(256), 0, stream>>>(qkv, ws);
    attn_kernel<<<dim3(1024), dim3(256), 0, stream>>>(ws, mask, out);
}